// Round 11
// baseline (198.916 us; speedup 1.0000x reference)
//
#include <hip/hip_runtime.h>
#include <hip/hip_bf16.h>

// Problem constants
#define BB 2
#define TT 2048
#define DD 1024
#define HH 16
#define DH 64
#define RR 16
#define BT (BB*TT)      // 4096
#define BH (BB*HH)      // 32
#define D3 (3*DD)       // 3072
#define NC 1536         // fused GEMM1 N: 1024 V + 256 q_lr + 256 k_lr
#define LOG2E 1.4426950408889634f

typedef __bf16 bf16x8 __attribute__((ext_vector_type(8)));
typedef float f32x4 __attribute__((ext_vector_type(4)));
typedef short short4v __attribute__((ext_vector_type(4)));

__device__ __forceinline__ float bf2f(unsigned short u) {
  unsigned int v = ((unsigned int)u) << 16;
  return __builtin_bit_cast(float, v);
}
__device__ __forceinline__ unsigned short f2bf(float f) {
  unsigned int x = __builtin_bit_cast(unsigned int, f);
  unsigned int r = x + 0x7fffu + ((x >> 16) & 1u);
  return (unsigned short)(r >> 16);
}
// HW packed cvt: v_cvt_pk_bf16_f32 (RNE, same numerics as f2bf)
__device__ __forceinline__ short4v pack_bf16x4(float a, float b, float c, float d) {
  __hip_bfloat162 lo = __float22bfloat162_rn(make_float2(a, b));
  __hip_bfloat162 hi = __float22bfloat162_rn(make_float2(c, d));
  uint2 u;
  __builtin_memcpy(&u.x, &lo, 4);
  __builtin_memcpy(&u.y, &hi, 4);
  return __builtin_bit_cast(short4v, u);
}

#define NEG_BIG (-1e30f)

__device__ __forceinline__ void async_copy16(const void* g, void* l) {
  __builtin_amdgcn_global_load_lds((const __attribute__((address_space(1))) void*)g,
                                   (__attribute__((address_space(3))) void*)l, 16, 0, 0);
}

// ---------------- fp32 -> bf16 elementwise convert ---------------------------------
__global__ __launch_bounds__(256) void cvt_f32_bf16(const float* __restrict__ in,
                                                    unsigned short* __restrict__ out,
                                                    int n) {
  int i = (blockIdx.x * 256 + threadIdx.x) * 8;
  if (i >= n) return;
  float4 a = *(const float4*)&in[i];
  float4 b = *(const float4*)&in[i + 4];
  uint4 o;
  uint2 u0 = __builtin_bit_cast(uint2, pack_bf16x4(a.x, a.y, a.z, a.w));
  uint2 u1 = __builtin_bit_cast(uint2, pack_bf16x4(b.x, b.y, b.z, b.w));
  o.x = u0.x; o.y = u0.y; o.z = u1.x; o.w = u1.y;
  *(uint4*)&out[i] = o;
}

// ---------------- transpose+cvt: out[j][d] = in[d][coff+j], fp32->bf16 --------------
__global__ __launch_bounds__(256) void transpose_cvt(const float* __restrict__ in,
                                                     unsigned short* __restrict__ out,
                                                     int R, int C, int coff) {
  __shared__ float tile[32][33];
  const int tx = threadIdx.x, ty = threadIdx.y;
  const int x = blockIdx.x * 32 + tx;
  const int y0 = blockIdx.y * 32;
#pragma unroll
  for (int i = 0; i < 32; i += 8)
    tile[ty + i][tx] = in[(size_t)(y0 + ty + i) * C + coff + x];
  __syncthreads();
  const int xo = y0 + tx;
  const int yo0 = blockIdx.x * 32;
#pragma unroll
  for (int i = 0; i < 32; i += 8)
    out[(size_t)(yo0 + ty + i) * R + xo] = f2bf(tile[tx][ty + i]);
}

// ---------------- combined LSR weights: Wcomb rows 1024..1535 ----------------------
// q-side scaled by core*0.25*LOG2E (flash softmax runs in exp2 domain).
__global__ __launch_bounds__(256) void build_lsr(const float* __restrict__ Wqkv,
                                                 const float* __restrict__ Wql,
                                                 const float* __restrict__ Wkl,
                                                 const float* __restrict__ core,
                                                 unsigned short* __restrict__ Wcomb_t) {
  const int d0 = blockIdx.x * 64, h = blockIdx.y, tid = threadIdx.x;
  __shared__ float Aq[64][65], Ak[64][65], Lq[64][16], Lk[64][16], cs[16];
#pragma unroll
  for (int p = 0; p < 16; p++) {
    int idx = p * 256 + tid, dd = idx >> 6, e = idx & 63;
    Aq[dd][e] = Wqkv[(size_t)(d0 + dd) * D3 + h * 64 + e];
    Ak[dd][e] = Wqkv[(size_t)(d0 + dd) * D3 + DD + h * 64 + e];
  }
#pragma unroll
  for (int p = 0; p < 4; p++) {
    int idx = p * 256 + tid, e = idx >> 4, r = idx & 15;
    Lq[e][r] = Wql[h * 1024 + e * 16 + r];
    Lk[e][r] = Wkl[h * 1024 + e * 16 + r];
  }
  if (tid < 16) cs[tid] = core[h * 16 + tid];
  __syncthreads();
  const int dd = tid & 63, rg = tid >> 6;
  float aq[4] = {}, ak[4] = {};
  for (int e = 0; e < 64; e++) {
    float xq = Aq[dd][e], xk = Ak[dd][e];
#pragma unroll
    for (int j = 0; j < 4; j++) {
      aq[j] += xq * Lq[e][rg * 4 + j];
      ak[j] += xk * Lk[e][rg * 4 + j];
    }
  }
#pragma unroll
  for (int j = 0; j < 4; j++) {
    int r = rg * 4 + j;
    Wcomb_t[(size_t)(1024 + h * 16 + r) * DD + d0 + dd] = f2bf(aq[j] * cs[r] * 0.25f * LOG2E);
    Wcomb_t[(size_t)(1280 + h * 16 + r) * DD + d0 + dd] = f2bf(ak[j]);
  }
}

// ---------------- bf16 GEMM core: 64x128 tile, BK=32, 4 waves 2x2, acc[2][4] --------
__device__ __forceinline__ void gemm64_core(const unsigned short* __restrict__ A,
                                            const unsigned short* __restrict__ Bt,
                                            int K, int bm, int bn,
                                            int tid, int g, int c, int wm, int wn,
                                            f32x4 acc[2][4]) {
  __shared__ __attribute__((aligned(16))) unsigned short As[64 * 32];
  __shared__ __attribute__((aligned(16))) unsigned short Bs[128 * 32];
  const int e0 = tid * 8;
  const int r0 = e0 >> 5, q0 = e0 & 31;
  const unsigned short* Arow = &A[(size_t)(bm * 64 + r0) * K + q0];
  const unsigned short* Brow0 = &Bt[(size_t)(bn * 128 + r0) * K + q0];
  const unsigned short* Brow1 = &Bt[(size_t)(bn * 128 + 64 + r0) * K + q0];
  for (int k0 = 0; k0 < K; k0 += 32) {
    __syncthreads();
    async_copy16(Arow + k0, &As[e0]);
    async_copy16(Brow0 + k0, &Bs[e0]);
    async_copy16(Brow1 + k0, &Bs[2048 + e0]);
    __syncthreads();
    bf16x8 af[2];
#pragma unroll
    for (int mt = 0; mt < 2; mt++)
      af[mt] = *(const bf16x8*)&As[(wm * 32 + mt * 16 + c) * 32 + g * 8];
#pragma unroll
    for (int nt = 0; nt < 4; nt++) {
      bf16x8 bf = *(const bf16x8*)&Bs[(wn * 64 + nt * 16 + c) * 32 + g * 8];
#pragma unroll
      for (int mt = 0; mt < 2; mt++)
        acc[mt][nt] = __builtin_amdgcn_mfma_f32_16x16x32_bf16(af[mt], bf, acc[mt][nt], 0, 0, 0);
    }
  }
}

// gemm2: C fp32 row-major
__global__ __launch_bounds__(256) void gemm64_f32(const unsigned short* __restrict__ A,
                                                  const unsigned short* __restrict__ Bt,
                                                  float* __restrict__ C,
                                                  int M, int N, int K) {
  const int tid = threadIdx.x, lane = tid & 63;
  const int g = lane >> 4, c = lane & 15;
  const int wid = tid >> 6, wm = wid >> 1, wn = wid & 1;
  const int bm = blockIdx.y, bn = blockIdx.x;
  f32x4 acc[2][4] = {};
  gemm64_core(A, Bt, K, bm, bn, tid, g, c, wm, wn, acc);
#pragma unroll
  for (int mt = 0; mt < 2; mt++)
#pragma unroll
    for (int nt = 0; nt < 4; nt++)
#pragma unroll
      for (int r = 0; r < 4; r++) {
        int row = bm * 64 + wm * 32 + mt * 16 + g * 4 + r;
        int col = bn * 128 + wn * 64 + nt * 16 + c;
        C[(size_t)row * N + col] = acc[mt][nt][r];
      }
}

// gemm1 fused: A = x_bf (4096x1024), Bt = Wcomb_t (1536x1024).
__global__ __launch_bounds__(256) void gemm_fused(const unsigned short* __restrict__ A,
                                                  const unsigned short* __restrict__ Bt,
                                                  unsigned short* __restrict__ qls,
                                                  unsigned short* __restrict__ klr,
                                                  unsigned short* __restrict__ vt,
                                                  int M, int N, int K) {
  const int tid = threadIdx.x, lane = tid & 63;
  const int g = lane >> 4, c = lane & 15;
  const int wid = tid >> 6, wm = wid >> 1, wn = wid & 1;
  const int bm = blockIdx.y, bn = blockIdx.x;
  f32x4 acc[2][4] = {};
  gemm64_core(A, Bt, K, bm, bn, tid, g, c, wm, wn, acc);
#pragma unroll
  for (int mt = 0; mt < 2; mt++)
#pragma unroll
    for (int nt = 0; nt < 4; nt++) {
      int colb = bn * 128 + wn * 64 + nt * 16;        // + c
      int tg0 = bm * 64 + wm * 32 + mt * 16 + g * 4;  // tokens tg0..tg0+3 (4-aligned)
      int b = tg0 >> 11, t0 = tg0 & 2047;
      if (colb < 1024) {
        int h = colb >> 6, d = (colb & 63) + c;
        uint2 pk = __builtin_bit_cast(uint2, pack_bf16x4(acc[mt][nt][0], acc[mt][nt][1],
                                                         acc[mt][nt][2], acc[mt][nt][3]));
        size_t idx = (size_t)(b * 16 + h) * (TT / 4) * 256 + (size_t)(t0 >> 2) * 256 + d * 4;
        *(uint2*)&vt[idx] = pk;
      } else if (colb < 1280) {
        int h = (colb - 1024) >> 4;
        size_t base = (size_t)(b * 16 + h) * TT;
#pragma unroll
        for (int r = 0; r < 4; r++)
          qls[(base + t0 + r) * 16 + c] = f2bf(acc[mt][nt][r]);
      } else {
        int h = (colb - 1280) >> 4;
        size_t base = (size_t)(b * 16 + h) * TT;
#pragma unroll
        for (int r = 0; r < 4; r++)
          klr[(base + t0 + r) * 16 + c] = f2bf(acc[mt][nt][r]);
      }
    }
}

// ---------------- Flash attention v8: v7 structure + VALU diet (hw pack, exp2) ------
// grid (16, BH), 256 thr = 4 waves. Block z handles Q-tiles B=(31-z) and A=z.
// Softmax in exp2 domain (log2e folded into q-side weights by build_lsr).
__global__ __launch_bounds__(256, 2) void flash_lsr(const unsigned short* __restrict__ qls,
                                                    const unsigned short* __restrict__ klr,
                                                    const unsigned short* __restrict__ vt,
                                                    unsigned short* __restrict__ attn) {
  const int z = blockIdx.x;             // 0..15
  const int bh = blockIdx.y, b = bh >> 4, h = bh & 15;
  const int tid = threadIdx.x, lane = tid & 63, w = tid >> 6;
  const int g = lane >> 4, c = lane & 15;
  const int q0_[2] = {(31 - z) * 64, z * 64};          // [0]=B (long), [1]=A (short)
  const int jmax_[2] = {(31 - z) >> 1, z >> 1};

  __shared__ __attribute__((aligned(16))) unsigned short Ks[2][128 * 20];  // 2x5.0 KB
  __shared__ __attribute__((aligned(16))) unsigned short Vs[2][32 * 264];  // 2x16.5 KB

  const size_t qbase = (size_t)bh * TT;
  short4v qf_[2];
  int qg_[2];
  float mi_[2], li_[2];
  f32x4 oa_[2][4] = {};
#pragma unroll
  for (int t = 0; t < 2; t++) {
    qf_[t] = __builtin_bit_cast(short4v,
        *(const uint2*)&qls[(qbase + q0_[t] + w * 16 + c) * 16 + g * 4]);
    qg_[t] = q0_[t] + w * 16 + c;
    mi_[t] = NEG_BIG;
    li_[t] = 0.f;
  }
  const f32x4 zero = {0.f, 0.f, 0.f, 0.f};
  const size_t kb = (size_t)bh * TT * 16;
  const size_t vb = (size_t)bh * TT * 64;
  const int srcl = g * 16 + g * 4;

  // prefetch j-tile 0 into registers
  uint4 kr = *(const uint4*)&klr[kb + tid * 8];
  uint4 vr[4];
#pragma unroll
  for (int p = 0; p < 4; p++)
    vr[p] = *(const uint4*)&vt[vb + (p * 256 + tid) * 8];

  int p = 0;
  f32x4 s_[2][8];

  auto stage = [&](int jt) {
    *(uint4*)&Ks[p][(tid >> 1) * 20 + (tid & 1) * 8] = kr;
#pragma unroll
    for (int q = 0; q < 4; q++) {
      int e = (q * 256 + tid) * 8;
      *(uint4*)&Vs[p][(e >> 8) * 264 + (e & 255)] = vr[q];
    }
    __syncthreads();
    if (jt < jmax_[0]) {
      kr = *(const uint4*)&klr[kb + (size_t)(jt + 1) * 2048 + tid * 8];
      const unsigned short* vp = &vt[vb + (size_t)(jt + 1) * 8192];
#pragma unroll
      for (int q = 0; q < 4; q++)
        vr[q] = *(const uint4*)&vp[(q * 256 + tid) * 8];
    }
  };
  auto qk = [&](int t) {
    const unsigned short* Kb = Ks[p];
#pragma unroll
    for (int nt = 0; nt < 8; nt++) {
      short4v kf = __builtin_bit_cast(short4v, *(const uint2*)&Kb[(nt * 16 + c) * 20 + g * 4]);
      s_[t][nt] = __builtin_amdgcn_mfma_f32_16x16x16bf16_1k(kf, qf_[t], zero, 0, 0, 0);
    }
  };
  auto msk = [&](int t, int jt) {
#pragma unroll
    for (int nt = 0; nt < 8; nt++)
#pragma unroll
      for (int r = 0; r < 4; r++) {
        int jg = jt * 128 + nt * 16 + g * 4 + r;
        if (jg > qg_[t]) s_[t][nt][r] = NEG_BIG;
      }
  };
  auto smax = [&](int t) {
    f32x4 vm = s_[t][0];
#pragma unroll
    for (int nt = 1; nt < 8; nt++)
#pragma unroll
      for (int r = 0; r < 4; r++) vm[r] = fmaxf(vm[r], s_[t][nt][r]);
    float rm = fmaxf(fmaxf(vm[0], vm[1]), fmaxf(vm[2], vm[3]));
    rm = fmaxf(rm, __shfl_xor(rm, 16, 64));
    rm = fmaxf(rm, __shfl_xor(rm, 32, 64));
    float mnew = fmaxf(mi_[t], rm);
    float alpha = exp2f(mi_[t] - mnew);   // exp2 domain
    mi_[t] = mnew;
    f32x4 vs = zero;
#pragma unroll
    for (int nt = 0; nt < 8; nt++)
#pragma unroll
      for (int r = 0; r < 4; r++) {
        float pv = exp2f(s_[t][nt][r] - mnew);
        s_[t][nt][r] = pv;
        vs[r] += pv;
      }
    float rs = (vs[0] + vs[1]) + (vs[2] + vs[3]);
    rs += __shfl_xor(rs, 16, 64);
    rs += __shfl_xor(rs, 32, 64);
    li_[t] = li_[t] * alpha + rs;
    float av[4];
#pragma unroll
    for (int r = 0; r < 4; r++) av[r] = __shfl(alpha, srcl + r, 64);
#pragma unroll
    for (int nd = 0; nd < 4; nd++)
#pragma unroll
      for (int r = 0; r < 4; r++) oa_[t][nd][r] *= av[r];
  };
  auto pv = [&](int t) {
    const unsigned short* Vb = Vs[p];
#pragma unroll
    for (int kc = 0; kc < 8; kc++) {
      short4v af = pack_bf16x4(s_[t][kc][0], s_[t][kc][1], s_[t][kc][2], s_[t][kc][3]);
#pragma unroll
      for (int nd = 0; nd < 4; nd++) {
        uint2 vv = *(const uint2*)&Vb[(kc * 4 + g) * 264 + (nd * 16 + c) * 4];
        short4v vf = __builtin_bit_cast(short4v, vv);
        oa_[t][nd] = __builtin_amdgcn_mfma_f32_16x16x16bf16_1k(af, vf, oa_[t][nd], 0, 0, 0);
      }
    }
  };

  int jt = 0;
  for (; jt <= jmax_[1]; jt++) {        // phase 1: both tiles, interleaved chains
    stage(jt);
    qk(0); qk(1);
    if (jt == jmax_[1]) msk(1, jt);     // A diag (B diag impossible here: jmaxA<jmaxB)
    smax(0); smax(1);
    pv(0); pv(1);
    p ^= 1;
  }
  for (; jt <= jmax_[0]; jt++) {        // phase 2: B only
    stage(jt);
    qk(0);
    if (jt == jmax_[0]) msk(0, jt);
    smax(0);
    pv(0);
    p ^= 1;
  }

  // epilogue: O in natural orientation; fold 1/li (per-q broadcast) and store
#pragma unroll
  for (int t = 0; t < 2; t++) {
    float inv = 1.f / li_[t];           // per q=c
    float iv[4];
#pragma unroll
    for (int r = 0; r < 4; r++) iv[r] = __shfl(inv, srcl + r, 64);
#pragma unroll
    for (int r = 0; r < 4; r++) {
      size_t rowb = ((size_t)b * TT + q0_[t] + w * 16 + g * 4 + r) * DD + h * 64;
#pragma unroll
      for (int nd = 0; nd < 4; nd++)
        attn[rowb + nd * 16 + c] = f2bf(oa_[t][nd][r] * iv[r]);
    }
  }
}

extern "C" void kernel_launch(void* const* d_in, const int* in_sizes, int n_in,
                              void* d_out, int out_size, void* d_ws, size_t ws_size,
                              hipStream_t stream) {
  const float* x      = (const float*)d_in[0];  // (B,T,1024) fp32
  const float* W_qkv  = (const float*)d_in[1];  // (1024,3072) fp32
  const float* W_qlsr = (const float*)d_in[2];  // (16,64,16)  fp32
  const float* W_klsr = (const float*)d_in[3];  // (16,64,16)  fp32
  const float* core   = (const float*)d_in[4];  // (16,16)     fp32
  const float* W_o    = (const float*)d_in[5];  // (1024,1024) fp32
  float* out = (float*)d_out;                   // (B,T,1024)  fp32

  char* ws = (char*)d_ws;
  unsigned short* x_bf    = (unsigned short*)ws; ws += (size_t)BT * DD * 2;
  unsigned short* Wcomb_t = (unsigned short*)ws; ws += (size_t)NC * DD * 2;
  unsigned short* Wo_t    = (unsigned short*)ws; ws += (size_t)DD * DD * 2;
  unsigned short* qls     = (unsigned short*)ws; ws += (size_t)BH * TT * 16 * 2;
  unsigned short* klr     = (unsigned short*)ws; ws += (size_t)BH * TT * 16 * 2;
  unsigned short* vt      = (unsigned short*)ws; ws += (size_t)BH * TT * 64 * 2;
  unsigned short* attn    = (unsigned short*)ws; ws += (size_t)BT * DD * 2;

  cvt_f32_bf16<<<(BT * DD) / (256 * 8), 256, 0, stream>>>(x, x_bf, BT * DD);
  transpose_cvt<<<dim3(32, 32), dim3(32, 8), 0, stream>>>(W_o, Wo_t, DD, DD, 0);
  transpose_cvt<<<dim3(32, 32), dim3(32, 8), 0, stream>>>(W_qkv, Wcomb_t, DD, D3, 2048);
  build_lsr<<<dim3(16, 16), 256, 0, stream>>>(W_qkv, W_qlsr, W_klsr, core, Wcomb_t);
  gemm_fused<<<dim3(NC / 128, BT / 64), 256, 0, stream>>>(x_bf, Wcomb_t, qls, klr, vt, BT, NC, DD);
  flash_lsr<<<dim3(16, BH), 256, 0, stream>>>(qls, klr, vt, attn);
  gemm64_f32<<<dim3(DD / 128, BT / 64), 256, 0, stream>>>(attn, Wo_t, out, BT, DD, DD);
}